// Round 1
// baseline (3839.784 us; speedup 1.0000x reference)
//
#include <hip/hip_runtime.h>

// ---------------------------------------------------------------------------
// LSTM: B=64, SEQ=512, I=1024, H=1024, O=512, fp32 in/out.
// Row space: n' = hid*4 + gate (gate-interleaved) so MFMA C-layout puts all
// 4 gate preacts of one (hid,batch) in ONE lane (acc[rr] = gate rr).
//   prep:   pack Wh4/Wx4 -> bf16 [n'=4096][1024], bias[n'], X->bf16,
//           h0 bf16 buffer, wT for output GEMM, zero barrier counters
//   phase1: Xg[t][jb][n'][b16] = X . Wx^T + bias (bf16 MFMA, m97 staging)
//   phase2: persistent recurrence.
//           R7 = R6 + TWO-GROUP SOFTWARE PIPELINE. R6 evidence: MfmaUtil
//           6.6 / VALUBusy 7.0 / HBM 2.1% -> step is a serial latency chain
//           (store drain -> RMW -> poll -> 32KB L3 load -> MFMA), nothing
//           overlaps. Now 64 blocks x 512 thr, each block runs batch groups
//           A=2*(blk&1), B=A+1 phase-shifted: B's staging loads fly during
//           MFMA A, A(t+1)'s flag+poll sits between phases and its staging
//           loads fly during MFMA B. Same register-pinned Wh frags serve
//           both groups (weights shared across batch). Wave0 stores/flags A,
//           wave1 stores/flags B, so neither lags twice per step.
//   out:    out[b][o] = h[b,:] . w[o,:]
// ---------------------------------------------------------------------------

typedef short short8 __attribute__((ext_vector_type(8)));   // 8 bf16
typedef float f32x4 __attribute__((ext_vector_type(4)));

typedef __attribute__((address_space(1))) const unsigned int glb_u32;
typedef __attribute__((address_space(3))) unsigned int lds_u32;

#define SEQL  512

// Epoch counters: one per batch-group jb, each on its own 128B line.
__device__ __attribute__((aligned(128))) unsigned g_bars[128];

__device__ __forceinline__ unsigned short f2bf(float f) {
    unsigned int u = __builtin_bit_cast(unsigned int, f);
    u += 0x7FFFu + ((u >> 16) & 1u);            // round-to-nearest-even
    return (unsigned short)(u >> 16);
}
__device__ __forceinline__ float bf2f(unsigned short s) {
    unsigned int u = ((unsigned int)s) << 16;
    return __builtin_bit_cast(float, u);
}
__device__ __forceinline__ float sigmoidf_fast(float x) {
    return 1.f / (1.f + __expf(-x));
}
__device__ __forceinline__ float tanhf_fast(float x) {
    return 1.f - 2.f / (1.f + __expf(2.f * x));
}
__device__ __forceinline__ void gld_lds16(const unsigned short* g, unsigned short* l) {
    __builtin_amdgcn_global_load_lds((glb_u32*)g, (lds_u32*)l, 16, 0, 0);
}

// --- prep: pack 4 gate weight mats (fp32 [1024][1024]) into bf16 [n'][1024]
__global__ void k_pack_w(const float* __restrict__ w0, const float* __restrict__ w1,
                         const float* __restrict__ w2, const float* __restrict__ w3,
                         unsigned short* __restrict__ dst) {
    int idx4 = blockIdx.x * blockDim.x + threadIdx.x;   // over 4096*256
    int np = idx4 >> 8;            // n' 0..4095
    int k4 = (idx4 & 255) * 4;
    int g = np & 3, r = np >> 2;
    const float* src = (g == 0) ? w0 : (g == 1) ? w1 : (g == 2) ? w2 : w3;
    float4 v = *(const float4*)(src + r * 1024 + k4);
    ushort4 o;
    o.x = f2bf(v.x); o.y = f2bf(v.y); o.z = f2bf(v.z); o.w = f2bf(v.w);
    *(ushort4*)(dst + (size_t)np * 1024 + k4) = o;
}

// --- prep: bias[n'], h0 bf16 [64][1024], wT (fp32 [1024][512]), zero counters
__global__ void k_misc(const float* __restrict__ b_hi, const float* __restrict__ b_xi,
                       const float* __restrict__ b_hf, const float* __restrict__ b_xf,
                       const float* __restrict__ b_ho, const float* __restrict__ b_xo,
                       const float* __restrict__ b_hg, const float* __restrict__ b_xg,
                       const float* __restrict__ h0, const float* __restrict__ w,
                       float* __restrict__ bias, unsigned short* __restrict__ hT0,
                       float* __restrict__ wT) {
    int idx = blockIdx.x * blockDim.x + threadIdx.x;
    if (idx < 4096) {
        int g = idx & 3, r = idx >> 2;                  // n'-order bias
        const float* bh = (g == 0) ? b_hi : (g == 1) ? b_hf : (g == 2) ? b_ho : b_hg;
        const float* bx = (g == 0) ? b_xi : (g == 1) ? b_xf : (g == 2) ? b_xo : b_xg;
        bias[idx] = bh[r] + bx[r];
    } else if (idx < 4096 + 65536) {
        int e = idx - 4096;                             // [b][hid]
        int k = e & 1023;
        hT0[e] = f2bf(h0[k]);
    } else if (idx < 4096 + 65536 + 524288) {
        int e = idx - 69632;
        int k = e >> 9, o = e & 511;
        wT[e] = w[o * 1024 + k];
    } else if (idx < 4096 + 65536 + 524288 + 128) {
        int e = idx - (4096 + 65536 + 524288);
        __hip_atomic_store(&g_bars[e], 0u, __ATOMIC_RELAXED, __HIP_MEMORY_SCOPE_AGENT);
    }
}

// --- prep: X fp32 -> bf16
__global__ void k_convert_x(const float* __restrict__ X, unsigned short* __restrict__ Xb) {
    int idx = blockIdx.x * blockDim.x + threadIdx.x;
    float4 v = ((const float4*)X)[idx];
    ushort4 o;
    o.x = f2bf(v.x); o.y = f2bf(v.y); o.z = f2bf(v.z); o.w = f2bf(v.w);
    ((ushort4*)Xb)[idx] = o;
}

// --- phase 1: Xg[t][jb][n'][b16], 128x128 tiles, m97 staging.
__global__ __launch_bounds__(256) void k_xgemm(const unsigned short* __restrict__ Wx,
                                               const unsigned short* __restrict__ Xb,
                                               const float* __restrict__ bias,
                                               unsigned short* __restrict__ Xg) {
    const int jt = blockIdx.x;          // col tile: t0=jt*2, 64 batches x 2 t
    const int n0 = blockIdx.y * 128;
    const int t0 = jt * 2;
    __shared__ unsigned short At[128 * 32];   // no pad: global_load_lds order
    __shared__ unsigned short Bt[128 * 32];
    const int tid = threadIdx.x;
    const int w   = tid >> 6;
    const int l   = tid & 63;
    const int l15 = l & 15, lq = l >> 4;
    const int wm  = w & 1, wn = w >> 1;
    const int seg = l & 3, cr = w * 16 + (l >> 2);

    const unsigned short* gA0 = Wx + (size_t)(n0 + cr) * 1024 + seg * 8;
    const unsigned short* gA1 = gA0 + (size_t)64 * 1024;
    const unsigned short* gB0 = Xb + ((size_t)cr * 512 + t0) * 1024 + seg * 8;
    const unsigned short* gB1 = gB0 + 1024;
    unsigned short* lA0 = At + w * 512;
    unsigned short* lA1 = At + 2048 + w * 512;
    unsigned short* lB0 = Bt + w * 512;
    unsigned short* lB1 = Bt + 2048 + w * 512;

    f32x4 acc[4][4];
#pragma unroll
    for (int mi = 0; mi < 4; ++mi)
#pragma unroll
        for (int nj = 0; nj < 4; ++nj)
            acc[mi][nj] = f32x4{0.f, 0.f, 0.f, 0.f};

    for (int kk = 0; kk < 32; ++kk) {
        __syncthreads();
        gld_lds16(gA0, lA0);
        gld_lds16(gA1, lA1);
        gld_lds16(gB0, lB0);
        gld_lds16(gB1, lB1);
        gA0 += 32; gA1 += 32; gB0 += 32; gB1 += 32;
        __syncthreads();
        short8 af[4], bfr[4];
#pragma unroll
        for (int mi = 0; mi < 4; ++mi)
            af[mi] = *(const short8*)(At + (wm * 64 + mi * 16 + l15) * 32 + lq * 8);
#pragma unroll
        for (int nj = 0; nj < 4; ++nj)
            bfr[nj] = *(const short8*)(Bt + (wn * 64 + nj * 16 + l15) * 32 + lq * 8);
#pragma unroll
        for (int mi = 0; mi < 4; ++mi)
#pragma unroll
            for (int nj = 0; nj < 4; ++nj)
                acc[mi][nj] = __builtin_amdgcn_mfma_f32_16x16x32_bf16(af[mi], bfr[nj], acc[mi][nj], 0, 0, 0);
    }

    // epilogue: col c = wn*64 + nj*16 + l15 -> t = t0+wn, jb = nj, b16 = l15
#pragma unroll
    for (int mi = 0; mi < 4; ++mi) {
#pragma unroll
        for (int rr = 0; rr < 4; ++rr) {
            int np = n0 + wm * 64 + mi * 16 + lq * 4 + rr;
            float bs = bias[np];
#pragma unroll
            for (int nj = 0; nj < 4; ++nj) {
                size_t idx = ((((size_t)(t0 + wn)) * 4 + nj) * 4096 + np) * 16 + l15;
                Xg[idx] = f2bf(acc[mi][nj][rr] + bs);
            }
        }
    }
}

// --- phase 2: persistent recurrence (R7: two-group software pipeline).
// 64 blocks x 512 thr: pair=blk&1 -> groups jbA=2*pair, jbB=2*pair+1;
// ibb=blk>>1 (n' rows [ibb*128,+128) = 32 hids x 4 gates). Wave w: rows
// ibb*128+w*16+[0,16). Lane (lq,l15): acc[rr] = gate-rr preact for
// hid=ibb*32+w*4+lq, batch=jb*16+l15. Same afrag serves both groups.
__global__ __launch_bounds__(512, 1) void k_rec(const unsigned short* __restrict__ Wh,
                                                const unsigned short* __restrict__ Xg,
                                                const float* __restrict__ c0,
                                                unsigned short* __restrict__ h0buf,
                                                unsigned short* __restrict__ h1buf) {
    const int blk  = blockIdx.x;
    const int pair = blk & 1;
    const int jbA  = pair * 2;
    const int jbB  = pair * 2 + 1;
    const int ibb  = blk >> 1;
    const int tid  = threadIdx.x;
    const int w    = tid >> 6;
    const int l    = tid & 63;
    const int l15  = l & 15, lq = l >> 4;

    __shared__ unsigned short hTl[16 * 1032];   // [b16][k=1024], stride 1032
    __shared__ unsigned short hTr[16 * 36];     // h transpose [b16][hid32], pad 36

    // Persistent A-fragments: rows n' = ibb*128 + w*16 + l15, all K.
    // (R3 evidence: pinned frags land in AGPRs; MFMA reads AGPR A-ops free.)
    short8 afrag[32];
    {
        const unsigned short* wrow = Wh + (size_t)(ibb * 128 + w * 16 + l15) * 1024;
#pragma unroll
        for (int ks = 0; ks < 32; ++ks)
            afrag[ks] = *(const short8*)(wrow + ks * 32 + lq * 8);
#pragma unroll
        for (int ks = 0; ks < 32; ++ks)
            asm volatile("" : "+v"(afrag[ks]));
    }

    const int hid = ibb * 32 + w * 4 + lq;     // this lane's hidden unit
    float cA = c0[hid];
    float cB = cA;

    // h staging mapping: thread -> (batch row sb, u64 lane sln)
    const int sb = tid >> 5, sln = tid & 31;
    const unsigned long long* pollA0 =
        (const unsigned long long*)h0buf + (size_t)(jbA * 16 + sb) * 256;
    const unsigned long long* pollA1 =
        (const unsigned long long*)h1buf + (size_t)(jbA * 16 + sb) * 256;
    const unsigned long long* pollB0 =
        (const unsigned long long*)h0buf + (size_t)(jbB * 16 + sb) * 256;
    const unsigned long long* pollB1 =
        (const unsigned long long*)h1buf + (size_t)(jbB * 16 + sb) * 256;

    unsigned* ctrA = &g_bars[jbA * 32];        // per-group epoch counters
    unsigned* ctrB = &g_bars[jbB * 32];

    // Xg fixed part: (( (t*4+jb)*4096 + ibb*128 + w*16 + lq*4 + rr )*16 + l15
    const size_t xg_fix = ((size_t)ibb * 128 + w * 16 + lq * 4) * 16 + l15;

    float xgA[4], xgB[4];
#pragma unroll
    for (int rr = 0; rr < 4; ++rr)
        xgA[rr] = bf2f(Xg[((size_t)jbA * 4096 + rr) * 16 + xg_fix]);   // t = 0
#pragma unroll
    for (int rr = 0; rr < 4; ++rr)
        xgB[rr] = bf2f(Xg[((size_t)jbB * 4096 + rr) * 16 + xg_fix]);   // t = 0

    // prologue: h_A(0) staging loads (h0buf; no poll needed, epoch 0 ready)
    unsigned long long tmpA[8];
#pragma unroll
    for (int p = 0; p < 8; ++p)
        tmpA[p] = __hip_atomic_load(pollA0 + p * 32 + sln,
                                    __ATOMIC_RELAXED, __HIP_MEMORY_SCOPE_AGENT);

    for (int t = 0; t < SEQL; ++t) {
        const unsigned long long* srcB    = (t & 1) ? pollB1 : pollB0;   // h_B(t)
        const unsigned long long* srcAnxt = (t & 1) ? pollA0 : pollA1;   // h_A(t+1)
        unsigned short* hdst = (t & 1) ? h0buf : h1buf;                  // h(t+1)

        // --- [A-stage] tmpA -> LDS (compiler inserts the vmcnt wait) ---
#pragma unroll
        for (int p = 0; p < 8; ++p)
            *(unsigned long long*)(&hTl[sb * 1032 + (p * 32 + sln) * 4]) = tmpA[p];
        __syncthreads();
        // (poll for h_B(t) already completed at end of previous iteration)

        // --- issue B staging loads; latency hides under MFMA A ---
        unsigned long long tmpB[8];
#pragma unroll
        for (int p = 0; p < 8; ++p)
            tmpB[p] = __hip_atomic_load(srcB + p * 32 + sln,
                                        __ATOMIC_RELAXED, __HIP_MEMORY_SCOPE_AGENT);

        // --- MFMA A over K=1024, two chains ---
        {
            f32x4 acc0 = {0.f, 0.f, 0.f, 0.f}, acc1 = {0.f, 0.f, 0.f, 0.f};
#pragma unroll
            for (int ks = 0; ks < 32; ks += 2) {
                short8 b0 = *(const short8*)(&hTl[l15 * 1032 + ks * 32 + lq * 8]);
                short8 b1 = *(const short8*)(&hTl[l15 * 1032 + (ks + 1) * 32 + lq * 8]);
                acc0 = __builtin_amdgcn_mfma_f32_16x16x32_bf16(afrag[ks], b0, acc0, 0, 0, 0);
                acc1 = __builtin_amdgcn_mfma_f32_16x16x32_bf16(afrag[ks + 1], b1, acc1, 0, 0, 0);
            }
            float pi = acc0[0] + acc1[0] + xgA[0];
            float pf = acc0[1] + acc1[1] + xgA[1];
            float po = acc0[2] + acc1[2] + xgA[2];
            float pg = acc0[3] + acc1[3] + xgA[3];
            float ig = sigmoidf_fast(pi);
            float fg = sigmoidf_fast(pf);
            float og = sigmoidf_fast(po);
            float gg = tanhf_fast(pg);
            cA = fg * cA + ig * gg;
            float hh = og * tanhf_fast(cA);
            hTr[l15 * 36 + w * 4 + lq] = f2bf(hh);
        }
        __syncthreads();                         // hTr-A ready; MFMA-A LDS reads done

        // --- wave0: store h_A(t+1), 16 rows x 64B (64 lanes x 2 u64) ---
        if (w == 0) {
            int row = l >> 2, sg = l & 3;
            unsigned long long v0 = *(const unsigned long long*)(&hTr[row * 36 + sg * 8]);
            unsigned long long v1 = *(const unsigned long long*)(&hTr[row * 36 + sg * 8 + 4]);
            unsigned long long* dst = (unsigned long long*)hdst +
                (((size_t)(jbA * 16 + row) * 1024 + ibb * 32 + sg * 8) >> 2);
            __hip_atomic_store(dst,     v0, __ATOMIC_RELAXED, __HIP_MEMORY_SCOPE_AGENT);
            __hip_atomic_store(dst + 1, v1, __ATOMIC_RELAXED, __HIP_MEMORY_SCOPE_AGENT);
        }

        // --- [B-stage] tmpB -> LDS (WAR on hTl safe: sync above) ---
#pragma unroll
        for (int p = 0; p < 8; ++p)
            *(unsigned long long*)(&hTl[sb * 1032 + (p * 32 + sln) * 4]) = tmpB[p];
        __syncthreads();

        // --- flag A(t+1) then wait for all 32 A-producers ---
        if (t < SEQL - 1) {
            if (tid == 0) {
                asm volatile("s_waitcnt vmcnt(0)" ::: "memory");   // hA stores drained
                __hip_atomic_fetch_add(ctrA, 1u, __ATOMIC_RELAXED,
                                       __HIP_MEMORY_SCOPE_AGENT);
                unsigned tgt = 32u * (unsigned)(t + 1);
                while (__hip_atomic_load(ctrA, __ATOMIC_RELAXED,
                                         __HIP_MEMORY_SCOPE_AGENT) < tgt)
                    __builtin_amdgcn_s_sleep(2);
            }
        }
        __syncthreads();

        // --- issue A(t+1) staging loads; latency hides under MFMA B ---
        if (t < SEQL - 1) {
#pragma unroll
            for (int p = 0; p < 8; ++p)
                tmpA[p] = __hip_atomic_load(srcAnxt + p * 32 + sln,
                                            __ATOMIC_RELAXED, __HIP_MEMORY_SCOPE_AGENT);
        }

        // --- MFMA B over K=1024, two chains ---
        {
            f32x4 acc0 = {0.f, 0.f, 0.f, 0.f}, acc1 = {0.f, 0.f, 0.f, 0.f};
#pragma unroll
            for (int ks = 0; ks < 32; ks += 2) {
                short8 b0 = *(const short8*)(&hTl[l15 * 1032 + ks * 32 + lq * 8]);
                short8 b1 = *(const short8*)(&hTl[l15 * 1032 + (ks + 1) * 32 + lq * 8]);
                acc0 = __builtin_amdgcn_mfma_f32_16x16x32_bf16(afrag[ks], b0, acc0, 0, 0, 0);
                acc1 = __builtin_amdgcn_mfma_f32_16x16x32_bf16(afrag[ks + 1], b1, acc1, 0, 0, 0);
            }
            float pi = acc0[0] + acc1[0] + xgB[0];
            float pf = acc0[1] + acc1[1] + xgB[1];
            float po = acc0[2] + acc1[2] + xgB[2];
            float pg = acc0[3] + acc1[3] + xgB[3];
            float ig = sigmoidf_fast(pi);
            float fg = sigmoidf_fast(pf);
            float og = sigmoidf_fast(po);
            float gg = tanhf_fast(pg);
            cB = fg * cB + ig * gg;
            float hh = og * tanhf_fast(cB);
            hTr[l15 * 36 + w * 4 + lq] = f2bf(hh);
        }
        __syncthreads();                         // hTr-B ready; MFMA-B LDS reads done

        // --- wave1: store h_B(t+1) ---
        if (w == 1) {
            int row = l >> 2, sg = l & 3;
            unsigned long long v0 = *(const unsigned long long*)(&hTr[row * 36 + sg * 8]);
            unsigned long long v1 = *(const unsigned long long*)(&hTr[row * 36 + sg * 8 + 4]);
            unsigned long long* dst = (unsigned long long*)hdst +
                (((size_t)(jbB * 16 + row) * 1024 + ibb * 32 + sg * 8) >> 2);
            __hip_atomic_store(dst,     v0, __ATOMIC_RELAXED, __HIP_MEMORY_SCOPE_AGENT);
            __hip_atomic_store(dst + 1, v1, __ATOMIC_RELAXED, __HIP_MEMORY_SCOPE_AGENT);
        }

        // --- flag B(t+1) + poll for next iteration's B consumption (wave1);
        //     Xg prefetch overlaps the poll. Next iter's [A-stage] sync
        //     orders the poll result before the tmpB loads. ---
        if (t < SEQL - 1) {
            if (tid == 64) {
                asm volatile("s_waitcnt vmcnt(0)" ::: "memory");   // hB stores drained
                __hip_atomic_fetch_add(ctrB, 1u, __ATOMIC_RELAXED,
                                       __HIP_MEMORY_SCOPE_AGENT);
                unsigned tgt = 32u * (unsigned)(t + 1);
                while (__hip_atomic_load(ctrB, __ATOMIC_RELAXED,
                                         __HIP_MEMORY_SCOPE_AGENT) < tgt)
                    __builtin_amdgcn_s_sleep(2);
            }
            size_t baseA = (((size_t)(t + 1) * 4 + jbA) * 4096) * 16 + xg_fix;
            size_t baseB = (((size_t)(t + 1) * 4 + jbB) * 4096) * 16 + xg_fix;
#pragma unroll
            for (int rr = 0; rr < 4; ++rr)
                xgA[rr] = bf2f(Xg[baseA + (size_t)rr * 16]);
#pragma unroll
            for (int rr = 0; rr < 4; ++rr)
                xgB[rr] = bf2f(Xg[baseB + (size_t)rr * 16]);
        }
    }
    // t=511 writes hdst = h0buf: final h (both groups) in h0buf
}

// --- output: out[b][o] = sum_k h[b][k] * w[o][k]
__global__ __launch_bounds__(256) void k_out(const unsigned short* __restrict__ hT,
                                             const float* __restrict__ wT,
                                             float* __restrict__ out) {
    const int b = blockIdx.x;
    const int tid = threadIdx.x;
    __shared__ float hs[1024];
#pragma unroll
    for (int p = 0; p < 4; ++p)
        hs[p * 256 + tid] = bf2f(hT[b * 1024 + p * 256 + tid]);
    __syncthreads();
    float a0 = 0.f, a1 = 0.f;
    for (int k = 0; k < 1024; ++k) {
        float hv = hs[k];
        a0 = fmaf(hv, wT[k * 512 + tid], a0);
        a1 = fmaf(hv, wT[k * 512 + 256 + tid], a1);
    }
    out[b * 512 + tid] = a0;
    out[b * 512 + 256 + tid] = a1;
}

extern "C" void kernel_launch(void* const* d_in, const int* in_sizes, int n_in,
                              void* d_out, int out_size, void* d_ws, size_t ws_size,
                              hipStream_t stream) {
    const float* X    = (const float*)d_in[0];
    const float* c0   = (const float*)d_in[1];
    const float* h0   = (const float*)d_in[2];
    const float* w_hi = (const float*)d_in[3];
    const float* w_xi = (const float*)d_in[4];
    const float* b_hi = (const float*)d_in[5];
    const float* b_xi = (const float*)d_in[6];
    const float* w_hf = (const float*)d_in[7];
    const float* w_xf = (const float*)d_in[8];
    const float* b_hf = (const float*)d_in[9];
    const float* b_xf = (const float*)d_in[10];
    const float* w_ho = (const float*)d_in[11];
    const float* w_xo = (const float*)d_in[12];
    const float* b_ho = (const float*)d_in[13];
    const float* b_xo = (const float*)d_in[14];
    const float* w_hg = (const float*)d_in[15];
    const float* w_xg = (const float*)d_in[16];
    const float* b_hg = (const float*)d_in[17];
    const float* b_xg = (const float*)d_in[18];
    const float* w    = (const float*)d_in[19];

    // workspace layout (16B aligned); ~338 MiB
    char* ws = (char*)d_ws;
    size_t off = 0;
    unsigned short* Xg  = (unsigned short*)(ws + off); off += (size_t)512 * 4096 * 64 * 2;
    unsigned short* Whp = (unsigned short*)(ws + off); off += (size_t)4096 * 1024 * 2;
    unsigned short* Wxp = (unsigned short*)(ws + off); off += (size_t)4096 * 1024 * 2;
    unsigned short* Xb  = (unsigned short*)(ws + off); off += (size_t)64 * 512 * 1024 * 2;
    float*          bias= (float*)(ws + off);          off += (size_t)4096 * 4;
    float*          wT  = (float*)(ws + off);          off += (size_t)1024 * 512 * 4;
    unsigned short* hT0 = (unsigned short*)(ws + off); off += (size_t)64 * 1024 * 2;
    unsigned short* hT1 = (unsigned short*)(ws + off); off += (size_t)64 * 1024 * 2;
    if (ws_size < off) return;

    k_pack_w<<<4096, 256, 0, stream>>>(w_hi, w_hf, w_ho, w_hg, Whp);
    k_pack_w<<<4096, 256, 0, stream>>>(w_xi, w_xf, w_xo, w_xg, Wxp);
    k_misc<<<(4096 + 65536 + 524288 + 128 + 255) / 256, 256, 0, stream>>>(
        b_hi, b_xi, b_hf, b_xf, b_ho, b_xo, b_hg, b_xg, h0, w, bias, hT0, wT);
    k_convert_x<<<33554432 / 4 / 256, 256, 0, stream>>>(X, Xb);

    k_xgemm<<<dim3(256, 32), 256, 0, stream>>>(Wxp, Xb, bias, Xg);

    void* args[] = {(void*)&Whp, (void*)&Xg, (void*)&c0, (void*)&hT0, (void*)&hT1};
    hipLaunchCooperativeKernel((void*)k_rec, dim3(64), dim3(512), args, 0, stream);

    k_out<<<64, 256, 0, stream>>>(hT0, wT, (float*)d_out);
}

// Round 3
// 2053.451 us; speedup vs baseline: 1.8699x; 1.8699x over previous
//
#include <hip/hip_runtime.h>

// ---------------------------------------------------------------------------
// LSTM: B=64, SEQ=512, I=1024, H=1024, O=512, fp32 in/out.
// Row space: n' = hid*4 + gate (gate-interleaved) so MFMA C-layout puts all
// 4 gate preacts of one (hid,batch) in ONE lane (acc[rr] = gate rr).
//   prep:   pack Wh4/Wx4 -> bf16 [n'=4096][1024], bias[n'], X->bf16,
//           h0 bf16 buffer + poison bufs 1..3, wT for output GEMM
//   phase1: Xg[t][jb][n'][b16] = X . Wx^T + bias (bf16 MFMA, m97 staging)
//   phase2: persistent recurrence, 128 blocks x 512 thr (R6 layout).
//           R9 = R8 with the buffer-stride bug fixed. R8 post-mortem: one
//           h buffer is 64x1024 bf16 = 16384 u64 but code strided by 8192
//           -> buffers aliased, poison init raced h0 init, absmax 0.067.
//           Protocol re-audited and sound:
//           4 rotating h buffers; consumers poison retired buffers (NaN
//           0xFFFF.. - h finite so never collides); each thread polls ITS
//           8 u64s until != poison. Data arrival IS the flag (no counter,
//           no flag RMW, no flag->data round trip; barriers/step 4 -> 2).
//           WAR: poll(t) success => all producers stored h(t) => all staged
//           h(t-1) => poisoning buf[(t-1)&3] is safe. Stale-read: poison of
//           buf[t&3] drains (vmcnt(0)) before h(t-2) store is issued, and
//           consumer observed h(t-2) before polling buf[t&3] at t.
//   out:    out[b][o] = h[b,:] . w[o,:]
// ---------------------------------------------------------------------------

typedef short short8 __attribute__((ext_vector_type(8)));   // 8 bf16
typedef float f32x4 __attribute__((ext_vector_type(4)));

typedef __attribute__((address_space(1))) const unsigned int glb_u32;
typedef __attribute__((address_space(3))) unsigned int lds_u32;

#define SEQL  512
#define POISON 0xFFFFFFFFFFFFFFFFull
#define BUFU64 16384     // u64 words per h buffer: 64 rows x 256 u64

__device__ __forceinline__ unsigned short f2bf(float f) {
    unsigned int u = __builtin_bit_cast(unsigned int, f);
    u += 0x7FFFu + ((u >> 16) & 1u);            // round-to-nearest-even
    return (unsigned short)(u >> 16);
}
__device__ __forceinline__ float bf2f(unsigned short s) {
    unsigned int u = ((unsigned int)s) << 16;
    return __builtin_bit_cast(float, u);
}
__device__ __forceinline__ float sigmoidf_fast(float x) {
    return 1.f / (1.f + __expf(-x));
}
__device__ __forceinline__ float tanhf_fast(float x) {
    return 1.f - 2.f / (1.f + __expf(2.f * x));
}
__device__ __forceinline__ void gld_lds16(const unsigned short* g, unsigned short* l) {
    __builtin_amdgcn_global_load_lds((glb_u32*)g, (lds_u32*)l, 16, 0, 0);
}

// --- prep: pack 4 gate weight mats (fp32 [1024][1024]) into bf16 [n'][1024]
__global__ void k_pack_w(const float* __restrict__ w0, const float* __restrict__ w1,
                         const float* __restrict__ w2, const float* __restrict__ w3,
                         unsigned short* __restrict__ dst) {
    int idx4 = blockIdx.x * blockDim.x + threadIdx.x;   // over 4096*256
    int np = idx4 >> 8;            // n' 0..4095
    int k4 = (idx4 & 255) * 4;
    int g = np & 3, r = np >> 2;
    const float* src = (g == 0) ? w0 : (g == 1) ? w1 : (g == 2) ? w2 : w3;
    float4 v = *(const float4*)(src + r * 1024 + k4);
    ushort4 o;
    o.x = f2bf(v.x); o.y = f2bf(v.y); o.z = f2bf(v.z); o.w = f2bf(v.w);
    *(ushort4*)(dst + (size_t)np * 1024 + k4) = o;
}

// --- prep: bias[n'], h0 bf16 buf0, poison bufs 1..3, wT (fp32 [1024][512])
__global__ void k_misc(const float* __restrict__ b_hi, const float* __restrict__ b_xi,
                       const float* __restrict__ b_hf, const float* __restrict__ b_xf,
                       const float* __restrict__ b_ho, const float* __restrict__ b_xo,
                       const float* __restrict__ b_hg, const float* __restrict__ b_xg,
                       const float* __restrict__ h0, const float* __restrict__ w,
                       float* __restrict__ bias, unsigned short* __restrict__ hbuf,
                       float* __restrict__ wT) {
    int idx = blockIdx.x * blockDim.x + threadIdx.x;
    if (idx < 4096) {
        int g = idx & 3, r = idx >> 2;                  // n'-order bias
        const float* bh = (g == 0) ? b_hi : (g == 1) ? b_hf : (g == 2) ? b_ho : b_hg;
        const float* bx = (g == 0) ? b_xi : (g == 1) ? b_xf : (g == 2) ? b_xo : b_xg;
        bias[idx] = bh[r] + bx[r];
    } else if (idx < 4096 + 65536) {
        int e = idx - 4096;                             // buf0: [b][hid] = h0
        int k = e & 1023;
        hbuf[e] = f2bf(h0[k]);
    } else if (idx < 4096 + 65536 + 524288) {
        int e = idx - 69632;
        int k = e >> 9, o = e & 511;
        wT[e] = w[o * 1024 + k];
    } else if (idx < 4096 + 65536 + 524288 + 3 * BUFU64) {
        int e = idx - (4096 + 65536 + 524288);          // poison bufs 1..3
        ((unsigned long long*)hbuf)[BUFU64 + e] = POISON;
    }
}

// --- prep: X fp32 -> bf16
__global__ void k_convert_x(const float* __restrict__ X, unsigned short* __restrict__ Xb) {
    int idx = blockIdx.x * blockDim.x + threadIdx.x;
    float4 v = ((const float4*)X)[idx];
    ushort4 o;
    o.x = f2bf(v.x); o.y = f2bf(v.y); o.z = f2bf(v.z); o.w = f2bf(v.w);
    ((ushort4*)Xb)[idx] = o;
}

// --- phase 1: Xg[t][jb][n'][b16], 128x128 tiles, m97 staging.
__global__ __launch_bounds__(256) void k_xgemm(const unsigned short* __restrict__ Wx,
                                               const unsigned short* __restrict__ Xb,
                                               const float* __restrict__ bias,
                                               unsigned short* __restrict__ Xg) {
    const int jt = blockIdx.x;          // col tile: t0=jt*2, 64 batches x 2 t
    const int n0 = blockIdx.y * 128;
    const int t0 = jt * 2;
    __shared__ unsigned short At[128 * 32];   // no pad: global_load_lds order
    __shared__ unsigned short Bt[128 * 32];
    const int tid = threadIdx.x;
    const int w   = tid >> 6;
    const int l   = tid & 63;
    const int l15 = l & 15, lq = l >> 4;
    const int wm  = w & 1, wn = w >> 1;
    const int seg = l & 3, cr = w * 16 + (l >> 2);

    const unsigned short* gA0 = Wx + (size_t)(n0 + cr) * 1024 + seg * 8;
    const unsigned short* gA1 = gA0 + (size_t)64 * 1024;
    const unsigned short* gB0 = Xb + ((size_t)cr * 512 + t0) * 1024 + seg * 8;
    const unsigned short* gB1 = gB0 + 1024;
    unsigned short* lA0 = At + w * 512;
    unsigned short* lA1 = At + 2048 + w * 512;
    unsigned short* lB0 = Bt + w * 512;
    unsigned short* lB1 = Bt + 2048 + w * 512;

    f32x4 acc[4][4];
#pragma unroll
    for (int mi = 0; mi < 4; ++mi)
#pragma unroll
        for (int nj = 0; nj < 4; ++nj)
            acc[mi][nj] = f32x4{0.f, 0.f, 0.f, 0.f};

    for (int kk = 0; kk < 32; ++kk) {
        __syncthreads();
        gld_lds16(gA0, lA0);
        gld_lds16(gA1, lA1);
        gld_lds16(gB0, lB0);
        gld_lds16(gB1, lB1);
        gA0 += 32; gA1 += 32; gB0 += 32; gB1 += 32;
        __syncthreads();
        short8 af[4], bfr[4];
#pragma unroll
        for (int mi = 0; mi < 4; ++mi)
            af[mi] = *(const short8*)(At + (wm * 64 + mi * 16 + l15) * 32 + lq * 8);
#pragma unroll
        for (int nj = 0; nj < 4; ++nj)
            bfr[nj] = *(const short8*)(Bt + (wn * 64 + nj * 16 + l15) * 32 + lq * 8);
#pragma unroll
        for (int mi = 0; mi < 4; ++mi)
#pragma unroll
            for (int nj = 0; nj < 4; ++nj)
                acc[mi][nj] = __builtin_amdgcn_mfma_f32_16x16x32_bf16(af[mi], bfr[nj], acc[mi][nj], 0, 0, 0);
    }

    // epilogue: col c = wn*64 + nj*16 + l15 -> t = t0+wn, jb = nj, b16 = l15
#pragma unroll
    for (int mi = 0; mi < 4; ++mi) {
#pragma unroll
        for (int rr = 0; rr < 4; ++rr) {
            int np = n0 + wm * 64 + mi * 16 + lq * 4 + rr;
            float bs = bias[np];
#pragma unroll
            for (int nj = 0; nj < 4; ++nj) {
                size_t idx = ((((size_t)(t0 + wn)) * 4 + nj) * 4096 + np) * 16 + l15;
                Xg[idx] = f2bf(acc[mi][nj][rr] + bs);
            }
        }
    }
}

// --- phase 2: persistent recurrence (R9: poison data-poll, 4 h buffers).
// 128 blocks x 512 thr: jb=blk&3 (16 batches), ibb=blk>>2 (n' rows
// [ibb*128,+128) = 32 hids x 4 gates). Wave w: rows ibb*128+w*16+[0,16).
// Lane (lq,l15): acc[rr] = gate-rr preact for hid=ibb*32+w*4+lq, b=jb*16+l15.
// hbuf = 4 x bf16[64][1024] (BUFU64=16384 u64 each); buf[t&3] holds h(t);
// h(t+1) -> buf[(t+1)&3]; buf[(t-1)&3] poisoned at step t.
__global__ __launch_bounds__(512, 2) void k_rec(const unsigned short* __restrict__ Wh,
                                                const unsigned short* __restrict__ Xg,
                                                const float* __restrict__ c0,
                                                unsigned short* __restrict__ hbuf) {
    const int blk = blockIdx.x;
    const int jb  = blk & 3;
    const int ibb = blk >> 2;
    const int tid = threadIdx.x;
    const int w   = tid >> 6;
    const int l   = tid & 63;
    const int l15 = l & 15, lq = l >> 4;

    __shared__ unsigned short hTl[16 * 1032];   // [b16][k=1024], stride 1032
    __shared__ unsigned short hTr[16 * 36];     // h transpose [b16][hid32], pad 36

    // Persistent A-fragments: rows n' = ibb*128 + w*16 + l15, all K.
    // (R3 evidence: pinned frags land in AGPRs; MFMA reads AGPR A-ops free.)
    short8 afrag[32];
    {
        const unsigned short* wrow = Wh + (size_t)(ibb * 128 + w * 16 + l15) * 1024;
#pragma unroll
        for (int ks = 0; ks < 32; ++ks)
            afrag[ks] = *(const short8*)(wrow + ks * 32 + lq * 8);
#pragma unroll
        for (int ks = 0; ks < 32; ++ks)
            asm volatile("" : "+v"(afrag[ks]));
    }

    const int hid = ibb * 32 + w * 4 + lq;     // this lane's hidden unit
    float c = c0[hid];

    unsigned long long* hb64 = (unsigned long long*)hbuf;   // BUFU64 u64 / buffer

    // stage mapping: thread -> (batch row sb, u64 lane sln); covers the
    // group's full 16x1024 slice across the block (all-producer coverage).
    const int sb = tid >> 5, sln = tid & 31;
    const size_t prow = (size_t)(jb * 16 + sb) * 256;

    // store/poison mapping (tid < 128): own production region, 16 rows x 8 u64
    const int srow = tid >> 3, sseg = tid & 7;
    const size_t sidx = (size_t)(jb * 16 + srow) * 256 + ibb * 8 + sseg;

    // Xg fixed part: (( (t*4+jb)*4096 + ibb*128 + w*16 + lq*4 + rr )*16 + l15
    const size_t xg_fix = ((size_t)ibb * 128 + w * 16 + lq * 4) * 16 + l15;

    float xg[4];
#pragma unroll
    for (int rr = 0; rr < 4; ++rr)
        xg[rr] = bf2f(Xg[((size_t)jb * 4096 + rr) * 16 + xg_fix]);   // t = 0

    for (int t = 0; t < SEQL; ++t) {
        // --- phase 1: data-poll + stage into LDS (data arrival IS the flag) ---
        {
            const unsigned long long* src = hb64 + (size_t)(t & 3) * BUFU64 + prow;
            unsigned long long tmp[8];
#pragma unroll
            for (int p = 0; p < 8; ++p)
                tmp[p] = __hip_atomic_load(src + p * 32 + sln, __ATOMIC_RELAXED,
                                           __HIP_MEMORY_SCOPE_AGENT);
            for (;;) {
                int miss = 0;
#pragma unroll
                for (int p = 0; p < 8; ++p)
                    if (tmp[p] == POISON) miss |= 1 << p;
                if (!miss) break;
                __builtin_amdgcn_s_sleep(1);     // light backoff: 16K threads poll
#pragma unroll
                for (int p = 0; p < 8; ++p)
                    if (miss & (1 << p))
                        tmp[p] = __hip_atomic_load(src + p * 32 + sln, __ATOMIC_RELAXED,
                                                   __HIP_MEMORY_SCOPE_AGENT);
            }
#pragma unroll
            for (int p = 0; p < 8; ++p)
                *(unsigned long long*)(&hTl[sb * 1032 + (p * 32 + sln) * 4]) = tmp[p];
        }
        __syncthreads();   // stage complete => block saw ALL producers' h(t)

        // --- phase 2: poison retired buffer h(t-1), own region only ---
        if (tid < 128)
            __hip_atomic_store(hb64 + (size_t)((t + 3) & 3) * BUFU64 + sidx, POISON,
                               __ATOMIC_RELAXED, __HIP_MEMORY_SCOPE_AGENT);

        // --- phase 3: MFMA over K=1024 (two chains) + gates -> hTr ---
        {
            f32x4 acc0 = {0.f, 0.f, 0.f, 0.f}, acc1 = {0.f, 0.f, 0.f, 0.f};
#pragma unroll
            for (int ks = 0; ks < 32; ks += 2) {
                short8 b0 = *(const short8*)(&hTl[l15 * 1032 + ks * 32 + lq * 8]);
                short8 b1 = *(const short8*)(&hTl[l15 * 1032 + (ks + 1) * 32 + lq * 8]);
                acc0 = __builtin_amdgcn_mfma_f32_16x16x32_bf16(afrag[ks], b0, acc0, 0, 0, 0);
                acc1 = __builtin_amdgcn_mfma_f32_16x16x32_bf16(afrag[ks + 1], b1, acc1, 0, 0, 0);
            }
            float pi = acc0[0] + acc1[0] + xg[0];
            float pf = acc0[1] + acc1[1] + xg[1];
            float po = acc0[2] + acc1[2] + xg[2];
            float pg = acc0[3] + acc1[3] + xg[3];
            float ig = sigmoidf_fast(pi);
            float fg = sigmoidf_fast(pf);
            float og = sigmoidf_fast(po);
            float gg = tanhf_fast(pg);
            c = fg * c + ig * gg;
            float hh = og * tanhf_fast(c);
            hTr[l15 * 36 + w * 4 + lq] = f2bf(hh);
        }
        __syncthreads();   // hTr ready; also protects hTl reuse next iter

        // --- phase 4: h(t+1) store. vmcnt(0) first: poison (issued phase 2,
        //     covered by the MFMA phase) must be drained BEFORE this release. ---
        if (tid < 128) {
            unsigned long long v = *(const unsigned long long*)(&hTr[srow * 36 + sseg * 4]);
            asm volatile("s_waitcnt vmcnt(0)" ::: "memory");
            __hip_atomic_store(hb64 + (size_t)((t + 1) & 3) * BUFU64 + sidx, v,
                               __ATOMIC_RELAXED, __HIP_MEMORY_SCOPE_AGENT);
        }

        // --- phase 5: Xg prefetch for t+1 (overlaps store visibility) ---
        if (t < SEQL - 1) {
            size_t base = (((size_t)(t + 1) * 4 + jb) * 4096) * 16 + xg_fix;
#pragma unroll
            for (int rr = 0; rr < 4; ++rr)
                xg[rr] = bf2f(Xg[base + (size_t)rr * 16]);
        }
    }
    // t=511 writes buf[512&3] = buf0: final h in buf0 (= hbuf base)
}

// --- output: out[b][o] = sum_k h[b][k] * w[o][k]
__global__ __launch_bounds__(256) void k_out(const unsigned short* __restrict__ hT,
                                             const float* __restrict__ wT,
                                             float* __restrict__ out) {
    const int b = blockIdx.x;
    const int tid = threadIdx.x;
    __shared__ float hs[1024];
#pragma unroll
    for (int p = 0; p < 4; ++p)
        hs[p * 256 + tid] = bf2f(hT[b * 1024 + p * 256 + tid]);
    __syncthreads();
    float a0 = 0.f, a1 = 0.f;
    for (int k = 0; k < 1024; ++k) {
        float hv = hs[k];
        a0 = fmaf(hv, wT[k * 512 + tid], a0);
        a1 = fmaf(hv, wT[k * 512 + 256 + tid], a1);
    }
    out[b * 512 + tid] = a0;
    out[b * 512 + 256 + tid] = a1;
}

extern "C" void kernel_launch(void* const* d_in, const int* in_sizes, int n_in,
                              void* d_out, int out_size, void* d_ws, size_t ws_size,
                              hipStream_t stream) {
    const float* X    = (const float*)d_in[0];
    const float* c0   = (const float*)d_in[1];
    const float* h0   = (const float*)d_in[2];
    const float* w_hi = (const float*)d_in[3];
    const float* w_xi = (const float*)d_in[4];
    const float* b_hi = (const float*)d_in[5];
    const float* b_xi = (const float*)d_in[6];
    const float* w_hf = (const float*)d_in[7];
    const float* w_xf = (const float*)d_in[8];
    const float* b_hf = (const float*)d_in[9];
    const float* b_xf = (const float*)d_in[10];
    const float* w_ho = (const float*)d_in[11];
    const float* w_xo = (const float*)d_in[12];
    const float* b_ho = (const float*)d_in[13];
    const float* b_xo = (const float*)d_in[14];
    const float* w_hg = (const float*)d_in[15];
    const float* w_xg = (const float*)d_in[16];
    const float* b_hg = (const float*)d_in[17];
    const float* b_xg = (const float*)d_in[18];
    const float* w    = (const float*)d_in[19];

    // workspace layout (16B aligned); ~339 MiB
    char* ws = (char*)d_ws;
    size_t off = 0;
    unsigned short* Xg  = (unsigned short*)(ws + off); off += (size_t)512 * 4096 * 64 * 2;
    unsigned short* Whp = (unsigned short*)(ws + off); off += (size_t)4096 * 1024 * 2;
    unsigned short* Wxp = (unsigned short*)(ws + off); off += (size_t)4096 * 1024 * 2;
    unsigned short* Xb  = (unsigned short*)(ws + off); off += (size_t)64 * 512 * 1024 * 2;
    float*          bias= (float*)(ws + off);          off += (size_t)4096 * 4;
    float*          wT  = (float*)(ws + off);          off += (size_t)1024 * 512 * 4;
    unsigned short* hbuf= (unsigned short*)(ws + off); off += (size_t)4 * 64 * 1024 * 2;
    if (ws_size < off) return;

    k_pack_w<<<4096, 256, 0, stream>>>(w_hi, w_hf, w_ho, w_hg, Whp);
    k_pack_w<<<4096, 256, 0, stream>>>(w_xi, w_xf, w_xo, w_xg, Wxp);
    k_misc<<<(4096 + 65536 + 524288 + 3 * BUFU64 + 255) / 256, 256, 0, stream>>>(
        b_hi, b_xi, b_hf, b_xf, b_ho, b_xo, b_hg, b_xg, h0, w, bias, hbuf, wT);
    k_convert_x<<<33554432 / 4 / 256, 256, 0, stream>>>(X, Xb);

    k_xgemm<<<dim3(256, 32), 256, 0, stream>>>(Wxp, Xb, bias, Xg);

    void* args[] = {(void*)&Whp, (void*)&Xg, (void*)&c0, (void*)&hbuf};
    hipLaunchCooperativeKernel((void*)k_rec, dim3(128), dim3(512), args, 0, stream);

    k_out<<<64, 256, 0, stream>>>(hbuf, wT, (float*)d_out);
}